// Round 1
// 8571.809 us; speedup vs baseline: 1.4345x; 1.4345x over previous
//
#include <hip/hip_runtime.h>

#define V 32000
#define E 256
#define D 512
#define B 32
#define T 128
#define SS 128
#define PAD 3
#define BT 4096   // B*T
#define G4 2048   // 4*D
#define NBLK 128  // recurrence blocks
#define NTHR 512  // recurrence threads/block

typedef _Float16 f16;
typedef _Float16 f16x8 __attribute__((ext_vector_type(8)));
typedef _Float16 f16x2 __attribute__((ext_vector_type(2)));
typedef float f32x4 __attribute__((ext_vector_type(4)));

// ---------------------------------------------------------------- helpers
__device__ __forceinline__ void gld_lds16(const f16* g, f16* l) {
    __builtin_amdgcn_global_load_lds(
        (__attribute__((address_space(1))) void*)(const_cast<f16*>(g)),
        (__attribute__((address_space(3))) void*)(l),
        16, 0, 0);
}

__device__ __forceinline__ float sigf(float x) { return 1.f / (1.f + __expf(-x)); }

// device-coherent (agent-scope, sc1: bypasses non-coherent per-XCD L2) dword ops
__device__ __forceinline__ void st_coh(unsigned* p, unsigned v) {
    __hip_atomic_store(p, v, __ATOMIC_RELAXED, __HIP_MEMORY_SCOPE_AGENT);
}
__device__ __forceinline__ unsigned ld_coh(const unsigned* p) {
    return __hip_atomic_load(p, __ATOMIC_RELAXED, __HIP_MEMORY_SCOPE_AGENT);
}

__device__ __forceinline__ void dot8(float& acc, f16x8 w, f16x8 x) {
    union { f16x8 v; f16x2 h[4]; } W, X;
    W.v = w; X.v = x;
    acc = __builtin_amdgcn_fdot2(W.h[0], X.h[0], acc, false);
    acc = __builtin_amdgcn_fdot2(W.h[1], X.h[1], acc, false);
    acc = __builtin_amdgcn_fdot2(W.h[2], X.h[2], acc, false);
    acc = __builtin_amdgcn_fdot2(W.h[3], X.h[3], acc, false);
}

// ---------------------------------------------------------------- prep kernels
__global__ void convertv(const float* __restrict__ src, f16* __restrict__ dst, long n) {
    long i = ((long)blockIdx.x * blockDim.x + threadIdx.x) * 4;
    long stride = (long)gridDim.x * blockDim.x * 4;
    for (; i < n; i += stride) {
        float4 v = *(const float4*)(src + i);
        f16x2 p0; p0[0] = (f16)v.x; p0[1] = (f16)v.y;
        f16x2 p1; p1[0] = (f16)v.z; p1[1] = (f16)v.w;
        *(f16x2*)(dst + i)     = p0;
        *(f16x2*)(dst + i + 2) = p1;
    }
}

__global__ void bias_prep(const float* __restrict__ bih0, const float* __restrict__ bhh0,
                          const float* __restrict__ bih1, const float* __restrict__ bhh1,
                          float* __restrict__ BIH0, float* __restrict__ B1,
                          unsigned* __restrict__ flags) {
    int i = blockIdx.x * 256 + threadIdx.x;   // 2048 total
    BIH0[i] = bih0[i] + bhh0[i];
    B1[i]   = bih1[i] + bhh1[i];
    if (i < NBLK) flags[i] = 0;   // plain store; kernel-end flush publishes it
}

__global__ void embed_kernel(const int* __restrict__ ids, const float* __restrict__ emb,
                             f16* __restrict__ YH) {
    int m = blockIdx.x;      // 0..4095  (= b*T + t)
    int e = threadIdx.x;     // 0..255
    int id = ids[m];
    float v = (id == PAD) ? 0.f : emb[(long)id * E + e];
    YH[(long)m * E + e] = (f16)v;
}

// ---------------------------------------------------------------- MFMA GEMM (A[M,K] row-major, Bm[N,K] row-major, C'[v][n])
// MODE 0: logits -> out[b][v][t] (+bout),  n = b*T+t
// MODE 1: PRE0T[j][n] = C + bias[j]
template<int MODE>
__global__ __launch_bounds__(256) void gemm_bt(const f16* __restrict__ A, const f16* __restrict__ Bm,
                                               const float* __restrict__ bias, float* __restrict__ Cout,
                                               int K) {
    __shared__ f16 As[128 * 32];
    __shared__ f16 Bs[128 * 32];
    int tid  = threadIdx.x;
    int tileM = blockIdx.y * 128, tileN = blockIdx.x * 128;
    int wid = tid >> 6, lane = tid & 63;
    int wy = wid >> 1, wx = wid & 1;

    f32x4 acc[4][4] = {};

    const f16* agp = A  + (long)(tileM + (tid >> 2)) * K + (tid & 3) * 8;
    const f16* bgp = Bm + (long)(tileN + (tid >> 2)) * K + (tid & 3) * 8;
    f16* asl = As + tid * 8;
    f16* bsl = Bs + tid * 8;

    for (int k0 = 0; k0 < K; k0 += 32) {
        gld_lds16(agp + k0,            asl);
        gld_lds16(agp + (long)64 * K + k0, asl + 64 * 32);
        gld_lds16(bgp + k0,            bsl);
        gld_lds16(bgp + (long)64 * K + k0, bsl + 64 * 32);
        __syncthreads();

        int krun = (lane >> 4) * 8;
        f16x8 af[4], bf[4];
#pragma unroll
        for (int mt = 0; mt < 4; mt++)
            af[mt] = *(const f16x8*)&As[(wy * 64 + mt * 16 + (lane & 15)) * 32 + krun];
#pragma unroll
        for (int nt = 0; nt < 4; nt++)
            bf[nt] = *(const f16x8*)&Bs[(wx * 64 + nt * 16 + (lane & 15)) * 32 + krun];
#pragma unroll
        for (int mt = 0; mt < 4; mt++)
#pragma unroll
            for (int nt = 0; nt < 4; nt++)
                acc[mt][nt] = __builtin_amdgcn_mfma_f32_16x16x32_f16(af[mt], bf[nt], acc[mt][nt], 0, 0, 0);
        __syncthreads();
    }

    int col = lane & 15;
#pragma unroll
    for (int mt = 0; mt < 4; mt++) {
        int vrowbase = tileM + wy * 64 + mt * 16 + (lane >> 4) * 4;
#pragma unroll
        for (int nt = 0; nt < 4; nt++) {
            int n = tileN + wx * 64 + nt * 16 + col;
            f32x4 c = acc[mt][nt];
            if (MODE == 0) {
                int b_ = n >> 7, t_ = n & 127;
                long obase = (long)b_ * V * T + t_;
#pragma unroll
                for (int r = 0; r < 4; r++) {
                    int v_ = vrowbase + r;
                    Cout[obase + (long)v_ * T] = c[r] + bias[v_];
                }
            } else {
#pragma unroll
                for (int r = 0; r < 4; r++) {
                    int j = vrowbase + r;
                    Cout[(long)j * BT + n] = c[r] + bias[j];
                }
            }
        }
    }
}

// ---------------------------------------------------------------- recurrence
// 128 blocks x 512 threads, cooperative (co-residency guarantee only; no cg sync).
// Thread = (b_, dloc, gate): tid = b_*16 + dloc*4 + gate. d = (blk&7)*64 + (blk>>3)*4 + dloc.
// Pipelined: iteration i computes layer0 step t=i (i<T) AND layer1 step t=i-1 (i>0).
// Both consume only S0A[i], S1A[i-1]  -> ONE barrier per iteration.
// State arrays are write-once per slot (never a stale copy in any L2); producers
// publish via agent-scope (sc1 write-through) dword stores; barrier = flag array.
__global__ __launch_bounds__(NTHR) void recurrence(
    const f16* __restrict__ WHH0H, const f16* __restrict__ WIH1H, const f16* __restrict__ WHH1H,
    const float* __restrict__ PRE0T, const float* __restrict__ B1,
    const float* __restrict__ s0_in, const float* __restrict__ c0_in,
    float* __restrict__ S1ALL, f16* __restrict__ S0A, f16* __restrict__ S1A,
    f16* __restrict__ XH, unsigned* __restrict__ flags) {
    const int tid = threadIdx.x, blk = blockIdx.x;
    const int lane = tid & 63;

    // ---- init slot 0 (16384 f16 per state array; blocks 0..15 cover it)
    int gt = blk * NTHR + tid;
    if (gt < 8192) {
        float a0 = s0_in[2 * gt],         a1 = s0_in[2 * gt + 1];
        float b0 = s0_in[16384 + 2 * gt], b1v = s0_in[16384 + 2 * gt + 1];
        union { f16x2 h; unsigned u; } p0, p1;
        p0.h[0] = (f16)a0; p0.h[1] = (f16)a1;
        p1.h[0] = (f16)b0; p1.h[1] = (f16)b1v;
        st_coh((unsigned*)(S0A) + gt, p0.u);
        st_coh((unsigned*)(S1A) + gt, p1.u);
        S1ALL[2 * gt] = b0; S1ALL[2 * gt + 1] = b1v;
    }

    const int b_   = tid >> 4;          // 0..31
    const int dloc = (tid >> 2) & 3;    // 0..3
    const int gate = tid & 3;           // 0..3 (i,f,g,o)
    const int xcd = blk & 7, grp = blk >> 3;   // grp 0..15
    const int d = xcd * 64 + grp * 4 + dloc;   // 0..511
    const int j = gate * 512 + d;
    const f16x8* w0  = (const f16x8*)(WHH0H + (long)j * 512);
    const f16x8* w1i = (const f16x8*)(WIH1H + (long)j * 512);
    const f16x8* w1h = (const f16x8*)(WHH1H + (long)j * 512);
    const float b1j = B1[j];
    const int sidx = b_ * 512 + d;
    float c0r = c0_in[sidx];            // cell state lives in registers
    float c1r = c0_in[16384 + sidx];
    const float* pre = PRE0T + (long)j * BT + b_ * T;

    auto gbar = [&](unsigned ep) {
        asm volatile("s_waitcnt vmcnt(0)" ::: "memory");   // drain our sc1 stores
        __syncthreads();                                   // whole block drained
        if (tid == 0) st_coh(flags + blk, ep);             // arrive
        if (tid < NBLK) {
            while (ld_coh(flags + tid) < ep) __builtin_amdgcn_s_sleep(1);
        }
        asm volatile("" ::: "memory");                     // no hoisting of loads above poll
        __syncthreads();
    };

    gbar(1);   // slot-0 init visible everywhere

    for (int i = 0; i <= T; i++) {
        const f16x8* s0row = (const f16x8*)(S0A + (long)i * 16384 + b_ * 512);
        float a1a = 0.f, a1b = 0.f;
        float a2a = 0.f, a2b = 0.f, a2c = 0.f, a2d = 0.f;

        if (i < T) {            // layer-0 gate dot: w_hh0(j) . s0[i][b]
#pragma unroll 4
            for (int k = 0; k < 64; k += 2) {
                dot8(a1a, w0[k],     s0row[k]);
                dot8(a1b, w0[k + 1], s0row[k + 1]);
            }
        }
        if (i > 0) {            // layer-1 gate dot: w_ih1 . s0[i][b] + w_hh1 . s1[i-1][b]
            const f16x8* s1row = (const f16x8*)(S1A + (long)(i - 1) * 16384 + b_ * 512);
#pragma unroll 2
            for (int k = 0; k < 64; k += 2) {
                dot8(a2a, w1i[k],     s0row[k]);
                dot8(a2b, w1i[k + 1], s0row[k + 1]);
                dot8(a2c, w1h[k],     s1row[k]);
                dot8(a2d, w1h[k + 1], s1row[k + 1]);
            }
        }

        const int base4 = lane & ~3;
        float s0n = 0.f, s1n = 0.f;
        if (i < T) {
            float acc1 = a1a + a1b + pre[i];
            float gi = __shfl(acc1, base4 + 0, 64);
            float gf = __shfl(acc1, base4 + 1, 64);
            float gg = __shfl(acc1, base4 + 2, 64);
            float go = __shfl(acc1, base4 + 3, 64);
            float ii = sigf(gi), ff = sigf(gf), g2 = tanhf(gg), oo = sigf(go);
            c0r = ff * c0r + ii * g2;            // all 4 gate-lanes track identical c
            s0n = oo * tanhf(c0r);
        }
        if (i > 0) {
            float acc2 = a2a + a2b + a2c + a2d + b1j;
            float gi = __shfl(acc2, base4 + 0, 64);
            float gf = __shfl(acc2, base4 + 1, 64);
            float gg = __shfl(acc2, base4 + 2, 64);
            float go = __shfl(acc2, base4 + 3, 64);
            float ii = sigf(gi), ff = sigf(gf), g2 = tanhf(gg), oo = sigf(go);
            c1r = ff * c1r + ii * g2;
            s1n = oo * tanhf(c1r);
        }

        // ---- publish new state (pack adjacent-d pairs into dwords, sc1 write-through)
        if (i < T) {
            float s0p = __shfl_down(s0n, 4, 64);     // partner = dloc+1, gate 0
            if ((tid & 7) == 0) {                    // d even, gate 0
                union { f16x2 h; unsigned u; } pk;
                pk.h[0] = (f16)s0n; pk.h[1] = (f16)s0p;
                st_coh((unsigned*)(S0A + (long)(i + 1) * 16384 + sidx), pk.u);
            }
        }
        if (i > 0) {
            float s1p = __shfl_down(s1n, 4, 64);
            if ((tid & 7) == 0) {
                union { f16x2 h; unsigned u; } pk;
                pk.h[0] = (f16)s1n; pk.h[1] = (f16)s1p;
                st_coh((unsigned*)(S1A + (long)i * 16384 + sidx), pk.u);
            }
            if (gate == 0) {                         // consumed by later kernels only
                S1ALL[(long)i * 16384 + sidx] = s1n;
                XH[(long)(b_ * T + (i - 1)) * 1024 + d] = (f16)s1n;
            }
        }

        gbar((unsigned)(i + 2));
    }
}

// ---------------------------------------------------------------- batched attention
__global__ __launch_bounds__(256) void attention(const float* __restrict__ h,
                                                 const float* __restrict__ S1ALL,
                                                 f16* __restrict__ XH) {
    int b_ = blockIdx.y, t0 = blockIdx.x * 8;
    int tid = threadIdx.x;
    __shared__ float s1l[8][512];
    __shared__ float sc[8][SS];

    for (int q = 0; q < 16; q++) {
        int idx = q * 256 + tid;         // tt*512 + dd
        int tt = idx >> 9, dd = idx & 511;
        s1l[tt][dd] = S1ALL[(long)(t0 + tt + 1) * 16384 + b_ * 512 + dd];
    }
    __syncthreads();

    int tq = tid >> 5, kq = tid & 31;    // tq: t 0..7, kq: k-seg of 16 floats
    const float* hb = h + (long)b_ * SS * D;

    float s1r[16];
#pragma unroll
    for (int u = 0; u < 16; u++) s1r[u] = s1l[tq][kq * 16 + u];

    for (int s_ = 0; s_ < SS; s_++) {
        const float4* hr = (const float4*)(hb + s_ * D) + kq * 4;
        float partial = 0.f;
#pragma unroll
        for (int u = 0; u < 4; u++) {
            float4 hv = hr[u];
            partial += hv.x * s1r[u * 4 + 0] + hv.y * s1r[u * 4 + 1]
                     + hv.z * s1r[u * 4 + 2] + hv.w * s1r[u * 4 + 3];
        }
        for (int off = 16; off; off >>= 1) partial += __shfl_down(partial, off, 32);
        if (kq == 0) sc[tq][s_] = partial;
    }
    __syncthreads();

    {
        float m_ = -1e30f;
#pragma unroll
        for (int u = 0; u < 4; u++) m_ = fmaxf(m_, sc[tq][kq * 4 + u]);
        for (int off = 16; off; off >>= 1) m_ = fmaxf(m_, __shfl_down(m_, off, 32));
        m_ = __shfl(m_, 0, 32);
        float ex[4], sum = 0.f;
#pragma unroll
        for (int u = 0; u < 4; u++) { ex[u] = __expf(sc[tq][kq * 4 + u] - m_); sum += ex[u]; }
        for (int off = 16; off; off >>= 1) sum += __shfl_down(sum, off, 32);
        sum = __shfl(sum, 0, 32);
        float inv = 1.f / sum;
        __syncthreads();
#pragma unroll
        for (int u = 0; u < 4; u++) sc[tq][kq * 4 + u] = ex[u] * inv;
    }
    __syncthreads();

    float za[8], zb[8];
#pragma unroll
    for (int tt = 0; tt < 8; tt++) { za[tt] = 0.f; zb[tt] = 0.f; }
    for (int s_ = 0; s_ < SS; s_++) {
        float h1 = hb[s_ * D + tid];
        float h2 = hb[s_ * D + 256 + tid];
#pragma unroll
        for (int tt = 0; tt < 8; tt++) {
            float a = sc[tt][s_];
            za[tt] += a * h1;
            zb[tt] += a * h2;
        }
    }
#pragma unroll
    for (int tt = 0; tt < 8; tt++) {
        long m = (long)b_ * T + t0 + tt;
        XH[m * 1024 + 512 + tid] = (f16)za[tt];
        XH[m * 1024 + 768 + tid] = (f16)zb[tt];
    }
}

// ---------------------------------------------------------------- launch
extern "C" void kernel_launch(void* const* d_in, const int* in_sizes, int n_in,
                              void* d_out, int out_size, void* d_ws, size_t ws_size,
                              hipStream_t stream) {
    const int*   tar  = (const int*)d_in[0];
    const float* h    = (const float*)d_in[1];
    const float* s0   = (const float*)d_in[2];
    const float* c0   = (const float*)d_in[3];
    const float* emb  = (const float*)d_in[4];
    const float* Wih0 = (const float*)d_in[5];
    const float* Whh0 = (const float*)d_in[6];
    const float* bih0 = (const float*)d_in[7];
    const float* bhh0 = (const float*)d_in[8];
    const float* Wih1 = (const float*)d_in[9];
    const float* Whh1 = (const float*)d_in[10];
    const float* bih1 = (const float*)d_in[11];
    const float* bhh1 = (const float*)d_in[12];
    const float* Wout = (const float*)d_in[13];
    const float* bout = (const float*)d_in[14];
    float* out = (float*)d_out;

    char* w = (char*)d_ws;
    f16* WOUTH = (f16*)w;  w += (size_t)V * 1024 * 2;
    f16* WIH0H = (f16*)w;  w += (size_t)G4 * E * 2;
    f16* WHH0H = (f16*)w;  w += (size_t)G4 * D * 2;
    f16* WIH1H = (f16*)w;  w += (size_t)G4 * D * 2;
    f16* WHH1H = (f16*)w;  w += (size_t)G4 * D * 2;
    f16* YH    = (f16*)w;  w += (size_t)BT * E * 2;
    f16* XH    = (f16*)w;  w += (size_t)BT * 1024 * 2;
    float* PRE0T = (float*)w; w += (size_t)G4 * BT * 4;
    float* S1ALL = (float*)w; w += (size_t)(T + 1) * B * D * 4;
    f16* S0A   = (f16*)w;  w += (size_t)(T + 1) * B * D * 2;   // write-once f16 layer-0 state
    f16* S1A   = (f16*)w;  w += (size_t)(T + 1) * B * D * 2;   // write-once f16 layer-1 state
    float* BIH0 = (float*)w; w += 2048 * 4;
    float* B1   = (float*)w; w += 2048 * 4;
    unsigned* flags = (unsigned*)w; w += 512;

    // weight conversions fp32 -> f16
    convertv<<<4096, 256, 0, stream>>>(Wout, WOUTH, (long)V * 1024);
    convertv<<<256,  256, 0, stream>>>(Wih0, WIH0H, (long)G4 * E);
    convertv<<<512,  256, 0, stream>>>(Whh0, WHH0H, (long)G4 * D);
    convertv<<<512,  256, 0, stream>>>(Wih1, WIH1H, (long)G4 * D);
    convertv<<<512,  256, 0, stream>>>(Whh1, WHH1H, (long)G4 * D);
    bias_prep<<<8, 256, 0, stream>>>(bih0, bhh0, bih1, bhh1, BIH0, B1, flags);
    embed_kernel<<<BT, 256, 0, stream>>>(tar, emb, YH);

    // PRE0T[j][m] = (emb[ids] @ Wih0^T + bih0 + bhh0), M=2048, N=4096, K=256
    gemm_bt<1><<<dim3(32, 16), 256, 0, stream>>>(WIH0H, YH, BIH0, PRE0T, 256);

    // sequential LSTM recurrence (cooperative launch for co-residency; custom barrier)
    void* args[] = { (void*)&WHH0H, (void*)&WIH1H, (void*)&WHH1H, (void*)&PRE0T, (void*)&B1,
                     (void*)&s0, (void*)&c0, (void*)&S1ALL, (void*)&S0A, (void*)&S1A,
                     (void*)&XH, (void*)&flags };
    hipLaunchCooperativeKernel(reinterpret_cast<void*>(recurrence), dim3(NBLK), dim3(NTHR),
                               args, 0, stream);

    // batched attention over all (b,t)
    attention<<<dim3(16, 32), 256, 0, stream>>>(h, S1ALL, XH);

    // logits: out[b][v][t] = [s1|z] @ Wout^T + bout, M=32000, N=4096, K=1024
    gemm_bt<0><<<dim3(32, 250), 256, 0, stream>>>(WOUTH, XH, bout, out, 1024);
}